// Round 5
// baseline (560.118 us; speedup 1.0000x reference)
//
#include <hip/hip_runtime.h>

#define D_IN 512
#define D_OUT 256

typedef short short8 __attribute__((ext_vector_type(8)));
typedef float floatx4 __attribute__((ext_vector_type(4)));

static __device__ __forceinline__ unsigned short f2bf(float f) {
    unsigned u = __float_as_uint(f);
    u += 0x7FFF + ((u >> 16) & 1);
    return (unsigned short)(u >> 16);
}
static __device__ __forceinline__ float bf2f(unsigned short h) {
    return __uint_as_float((unsigned)h << 16);
}

// ---------------- fused: W convert+transpose + cnt/partials zeroing ----------------
#define CONV_BLOCKS 256
__global__ __launch_bounds__(512) void convert_and_zero(const float* __restrict__ W,
                                                        unsigned short* __restrict__ Wt,
                                                        int* __restrict__ cnt, int NZ) {
    int b = blockIdx.x;
    if (b < CONV_BLOCKS) {
        int t = b * 512 + threadIdx.x;     // D_IN*D_OUT = 131072 = 256*512
        int n = t >> 9;
        int k = t & 511;
        Wt[t] = f2bf(W[(size_t)k * D_OUT + n]);
    } else {
        int i = (b - CONV_BLOCKS) * 512 + threadIdx.x;
        if (i < NZ) cnt[i] = 0;
    }
}

// ---------------- CSR histogram (4 edges/thread) ----------------
__global__ __launch_bounds__(256) void hist_rows(const int* __restrict__ rows,
                                                 int* __restrict__ cnt, int E) {
    int e0 = (blockIdx.x * 256 + threadIdx.x) * 4;
    if (e0 + 3 < E) {
        int4 r = *(const int4*)(rows + e0);
        atomicAdd(&cnt[r.x], 1);
        atomicAdd(&cnt[r.y], 1);
        atomicAdd(&cnt[r.z], 1);
        atomicAdd(&cnt[r.w], 1);
    } else {
        for (int e = e0; e < E; ++e) atomicAdd(&cnt[rows[e]], 1);
    }
}

// ---------------- single-dispatch scan, decoupled lookback (13 blocks) -----------
#define SCAN_B 4096
#define SCAN_READY (1 << 30)
__global__ __launch_bounds__(1024) void scan_blocks(const int* __restrict__ cnt,
                                                    int* __restrict__ ptr,
                                                    int* __restrict__ partials, int M) {
    __shared__ int wsum[16];
    __shared__ int s_off;
    const int t = threadIdx.x, lane = t & 63, wave = t >> 6;
    const int base = blockIdx.x * SCAN_B + t * 4;
    int4 v = make_int4(0, 0, 0, 0);
    if (base + 3 < M) v = *(const int4*)(cnt + base);
    else {
        if (base + 0 < M) v.x = cnt[base + 0];
        if (base + 1 < M) v.y = cnt[base + 1];
        if (base + 2 < M) v.z = cnt[base + 2];
        if (base + 3 < M) v.w = cnt[base + 3];
    }
    int s = v.x + v.y + v.z + v.w;
    int incl = s;
#pragma unroll
    for (int off = 1; off < 64; off <<= 1) {
        int x = __shfl_up(incl, off, 64);
        if (lane >= off) incl += x;
    }
    if (lane == 63) wsum[wave] = incl;
    __syncthreads();
    if (t == 0) {
        int run = 0;
#pragma unroll
        for (int w = 0; w < 16; ++w) { int x = wsum[w]; wsum[w] = run; run += x; }
        atomicExch(&partials[blockIdx.x], run | SCAN_READY);
        int off = 0;
        for (int j = 0; j < (int)blockIdx.x; ++j) {
            int pv;
            do { pv = atomicAdd(&partials[j], 0); } while (!(pv & SCAN_READY));
            off += pv & ~SCAN_READY;
        }
        s_off = off;
    }
    __syncthreads();
    int g = s_off + wsum[wave] + (incl - s);
    int e0 = g, e1 = e0 + v.x, e2 = e1 + v.y, e3 = e2 + v.z;
    if (base + 3 < M) *(int4*)(ptr + base) = make_int4(e0, e1, e2, e3);
    else {
        if (base + 0 < M) ptr[base + 0] = e0;
        if (base + 1 < M) ptr[base + 1] = e1;
        if (base + 2 < M) ptr[base + 2] = e2;
        if (base + 3 < M) ptr[base + 3] = e3;
    }
}

// ---------------- B-resident barrier-free GEMM + in-block edge placement ---------
// grid (128, 2), 576 threads (9 waves), 1 block/CU.
// LDS: full N-half of Wt (128 cols x 512 k bf16 = 128 KB), staged ONCE, one barrier.
// k-plane layout Bs[p][col][8] (p = k/8): staging writes 16B chunks with col inner
// (consecutive lanes -> contiguous LDS) and frag reads touch 16 contiguous 16B
// chunks per quarter-wave -> conflict-free both sides (verified pattern, R2/R4).
// Waves 0..7: each streams 16-row A tiles HBM->regs (depth-4 ping-pong, fully
// unrolled 16-step K loop, ZERO barriers) and does 128 MFMAs per tile.
// Wave 8: destructive CSR edge placement (shares the block -> true overlap).
__global__ __launch_bounds__(576) void gemm_build(
    const float* __restrict__ A, const unsigned short* __restrict__ Wt,
    unsigned short* __restrict__ S, int M,
    const float* __restrict__ vals, const int* __restrict__ rows,
    const int* __restrict__ cols, int* __restrict__ ptr,
    unsigned long long* __restrict__ edges, int E) {
    __shared__ unsigned short Bs[64 * 128 * 8];   // 128 KiB
    const int tid = threadIdx.x;
    const int bx  = blockIdx.x;
    const int ny  = blockIdx.y;

    // ---- stage N-half of Wt into LDS (8192 chunks of 16B) ----
    const unsigned short* wbase = Wt + (size_t)(ny * 128) * D_IN;
    for (int c = tid; c < 64 * 128; c += 576) {
        int p = c >> 7, col = c & 127;
        *(short8*)(Bs + (size_t)c * 8) =
            *(const short8*)(wbase + (size_t)col * D_IN + p * 8);
    }
    __syncthreads();   // the ONLY barrier

    const int wave = tid >> 6;
    const int lane = tid & 63;
    const int l15  = lane & 15;
    const int quad = lane >> 4;

    if (wave == 8) {
        // ---- build role: one slice of edges, destructive CSR placement ----
        const int nB  = gridDim.x * gridDim.y;              // 256
        const int b   = ny * gridDim.x + bx;
        const int per = (((E + nB - 1) / nB) + 3) & ~3;     // 16B-aligned slices
        const long base = (long)b * per;
        int count = (int)(E - base); if (count > per) count = per;
        for (int e = (int)base + lane * 4; e < base + count; e += 256) {
            int4   rr = *(const int4*)(rows + e);
            int4   cc = *(const int4*)(cols + e);
            float4 vv = *(const float4*)(vals + e);
            int p0 = atomicAdd(&ptr[rr.x], 1);
            __builtin_nontemporal_store(
                (unsigned long long)(unsigned)cc.x |
                ((unsigned long long)(unsigned)__float_as_int(vv.x) << 32), edges + p0);
            int p1 = atomicAdd(&ptr[rr.y], 1);
            __builtin_nontemporal_store(
                (unsigned long long)(unsigned)cc.y |
                ((unsigned long long)(unsigned)__float_as_int(vv.y) << 32), edges + p1);
            int p2 = atomicAdd(&ptr[rr.z], 1);
            __builtin_nontemporal_store(
                (unsigned long long)(unsigned)cc.z |
                ((unsigned long long)(unsigned)__float_as_int(vv.z) << 32), edges + p2);
            int p3 = atomicAdd(&ptr[rr.w], 1);
            __builtin_nontemporal_store(
                (unsigned long long)(unsigned)cc.w |
                ((unsigned long long)(unsigned)__float_as_int(vv.w) << 32), edges + p3);
        }
        return;
    }

    // ---- gemm role: waves 0..7, one 16-row tile per task ----
    const int nTiles = (M + 15) >> 4;
    for (int rt = bx * 8 + wave; rt < nTiles; rt += gridDim.x * 8) {
        const int row0 = rt << 4;
        int arow = row0 + l15; if (arow >= M) arow = M - 1;
        const float* ap = A + (size_t)arow * D_IN + quad * 8;

        floatx4 acc[8] = {};

        // depth-4 ping-pong prefetch (named regs; fully static indexing)
        float4 p0l, p0h, p1l, p1h, p2l, p2h, p3l, p3h;
        p0l = *(const float4*)(ap + 0);   p0h = *(const float4*)(ap + 4);
        p1l = *(const float4*)(ap + 32);  p1h = *(const float4*)(ap + 36);
        p2l = *(const float4*)(ap + 64);  p2h = *(const float4*)(ap + 68);
        p3l = *(const float4*)(ap + 96);  p3h = *(const float4*)(ap + 100);

#define STEP(T, PL, PH)                                                           \
        {                                                                         \
            short8 af;                                                            \
            af[0] = (short)f2bf(PL.x); af[1] = (short)f2bf(PL.y);                 \
            af[2] = (short)f2bf(PL.z); af[3] = (short)f2bf(PL.w);                 \
            af[4] = (short)f2bf(PH.x); af[5] = (short)f2bf(PH.y);                 \
            af[6] = (short)f2bf(PH.z); af[7] = (short)f2bf(PH.w);                 \
            if ((T) + 4 < 16) {                                                   \
                PL = *(const float4*)(ap + ((T) + 4) * 32);                       \
                PH = *(const float4*)(ap + ((T) + 4) * 32 + 4);                   \
            }                                                                     \
            const unsigned short* bb =                                            \
                Bs + ((size_t)((T) * 4 + quad) * 128 + l15) * 8;                  \
            _Pragma("unroll")                                                     \
            for (int c = 0; c < 8; ++c)                                           \
                acc[c] = __builtin_amdgcn_mfma_f32_16x16x32_bf16(                 \
                    af, *(const short8*)(bb + c * 128), acc[c], 0, 0, 0);         \
        }

        STEP(0,  p0l, p0h) STEP(1,  p1l, p1h) STEP(2,  p2l, p2h) STEP(3,  p3l, p3h)
        STEP(4,  p0l, p0h) STEP(5,  p1l, p1h) STEP(6,  p2l, p2h) STEP(7,  p3l, p3h)
        STEP(8,  p0l, p0h) STEP(9,  p1l, p1h) STEP(10, p2l, p2h) STEP(11, p3l, p3h)
        STEP(12, p0l, p0h) STEP(13, p1l, p1h) STEP(14, p2l, p2h) STEP(15, p3l, p3h)
#undef STEP

        // epilogue: row = row0 + quad*4 + r, col = ny*128 + c*16 + l15
#pragma unroll
        for (int c = 0; c < 8; ++c) {
#pragma unroll
            for (int r = 0; r < 4; ++r) {
                int gm = row0 + quad * 4 + r;
                if (gm < M)
                    S[(size_t)gm * D_OUT + ny * 128 + c * 16 + l15] = f2bf(acc[c][r]);
            }
        }
    }
}

// ---------------- Aggregate: one wave/row, 8-edge unroll, fp32 accum ----------------
// Reads shifted (destructive) CSR: row extent = [row ? ptr[row-1] : 0, ptr[row]).
__global__ __launch_bounds__(256) void spmm_rows(const unsigned short* __restrict__ S,
                                                 const int2* __restrict__ edges,
                                                 const int* __restrict__ ptr,
                                                 const float* __restrict__ bias,
                                                 float* __restrict__ out, int M) {
    const int row = blockIdx.x * 4 + (threadIdx.x >> 6);
    if (row >= M) return;
    const int lane = threadIdx.x & 63;
    float4 a0 = ((const float4*)bias)[lane];
    float4 a1 = make_float4(0.f, 0.f, 0.f, 0.f);
    const int beg = row ? ptr[row - 1] : 0;
    const int end = ptr[row];
    int j = beg;
    for (; j + 7 < end; j += 8) {
        int2 e0 = edges[j + 0], e1 = edges[j + 1], e2 = edges[j + 2], e3 = edges[j + 3];
        int2 e4 = edges[j + 4], e5 = edges[j + 5], e6 = edges[j + 6], e7 = edges[j + 7];
        ushort4 s0 = ((const ushort4*)(S + (size_t)e0.x * D_OUT))[lane];
        ushort4 s1 = ((const ushort4*)(S + (size_t)e1.x * D_OUT))[lane];
        ushort4 s2 = ((const ushort4*)(S + (size_t)e2.x * D_OUT))[lane];
        ushort4 s3 = ((const ushort4*)(S + (size_t)e3.x * D_OUT))[lane];
        ushort4 s4 = ((const ushort4*)(S + (size_t)e4.x * D_OUT))[lane];
        ushort4 s5 = ((const ushort4*)(S + (size_t)e5.x * D_OUT))[lane];
        ushort4 s6 = ((const ushort4*)(S + (size_t)e6.x * D_OUT))[lane];
        ushort4 s7 = ((const ushort4*)(S + (size_t)e7.x * D_OUT))[lane];
        float v0 = __int_as_float(e0.y), v1 = __int_as_float(e1.y);
        float v2 = __int_as_float(e2.y), v3 = __int_as_float(e3.y);
        float v4 = __int_as_float(e4.y), v5 = __int_as_float(e5.y);
        float v6 = __int_as_float(e6.y), v7 = __int_as_float(e7.y);
        a0.x += v0 * bf2f(s0.x) + v2 * bf2f(s2.x) + v4 * bf2f(s4.x) + v6 * bf2f(s6.x);
        a0.y += v0 * bf2f(s0.y) + v2 * bf2f(s2.y) + v4 * bf2f(s4.y) + v6 * bf2f(s6.y);
        a0.z += v0 * bf2f(s0.z) + v2 * bf2f(s2.z) + v4 * bf2f(s4.z) + v6 * bf2f(s6.z);
        a0.w += v0 * bf2f(s0.w) + v2 * bf2f(s2.w) + v4 * bf2f(s4.w) + v6 * bf2f(s6.w);
        a1.x += v1 * bf2f(s1.x) + v3 * bf2f(s3.x) + v5 * bf2f(s5.x) + v7 * bf2f(s7.x);
        a1.y += v1 * bf2f(s1.y) + v3 * bf2f(s3.y) + v5 * bf2f(s5.y) + v7 * bf2f(s7.y);
        a1.z += v1 * bf2f(s1.z) + v3 * bf2f(s3.z) + v5 * bf2f(s5.z) + v7 * bf2f(s7.z);
        a1.w += v1 * bf2f(s1.w) + v3 * bf2f(s3.w) + v5 * bf2f(s5.w) + v7 * bf2f(s7.w);
    }
    for (; j + 3 < end; j += 4) {
        int2 e0 = edges[j], e1 = edges[j + 1], e2 = edges[j + 2], e3 = edges[j + 3];
        ushort4 s0 = ((const ushort4*)(S + (size_t)e0.x * D_OUT))[lane];
        ushort4 s1 = ((const ushort4*)(S + (size_t)e1.x * D_OUT))[lane];
        ushort4 s2 = ((const ushort4*)(S + (size_t)e2.x * D_OUT))[lane];
        ushort4 s3 = ((const ushort4*)(S + (size_t)e3.x * D_OUT))[lane];
        float v0 = __int_as_float(e0.y), v1 = __int_as_float(e1.y);
        float v2 = __int_as_float(e2.y), v3 = __int_as_float(e3.y);
        a0.x += v0 * bf2f(s0.x) + v2 * bf2f(s2.x);
        a0.y += v0 * bf2f(s0.y) + v2 * bf2f(s2.y);
        a0.z += v0 * bf2f(s0.z) + v2 * bf2f(s2.z);
        a0.w += v0 * bf2f(s0.w) + v2 * bf2f(s2.w);
        a1.x += v1 * bf2f(s1.x) + v3 * bf2f(s3.x);
        a1.y += v1 * bf2f(s1.y) + v3 * bf2f(s3.y);
        a1.z += v1 * bf2f(s1.z) + v3 * bf2f(s3.z);
        a1.w += v1 * bf2f(s1.w) + v3 * bf2f(s3.w);
    }
    for (; j < end; ++j) {
        int2 e = edges[j];
        float v = __int_as_float(e.y);
        ushort4 s = ((const ushort4*)(S + (size_t)e.x * D_OUT))[lane];
        a0.x += v * bf2f(s.x);
        a0.y += v * bf2f(s.y);
        a0.z += v * bf2f(s.z);
        a0.w += v * bf2f(s.w);
    }
    a0.x += a1.x; a0.y += a1.y; a0.z += a1.z; a0.w += a1.w;
    floatx4 res = {a0.x, a0.y, a0.z, a0.w};
    __builtin_nontemporal_store(res, (floatx4*)(out + (size_t)row * D_OUT) + lane);
}

extern "C" void kernel_launch(void* const* d_in, const int* in_sizes, int n_in,
                              void* d_out, int out_size, void* d_ws, size_t ws_size,
                              hipStream_t stream) {
    const float* inputs    = (const float*)d_in[0];
    const float* weights   = (const float*)d_in[1];
    const float* bias      = (const float*)d_in[2];
    const float* edge_vals = (const float*)d_in[3];
    const int*   edge_row  = (const int*)d_in[4];
    const int*   edge_col  = (const int*)d_in[5];
    float* out = (float*)d_out;

    const int M = in_sizes[0] / D_IN;  // 50000
    const int E = in_sizes[3];         // 800000

    // Workspace:
    //   S: M*D_OUT bf16 | Wt: D_OUT*D_IN bf16 | edges: E u64 | ptr: M+1 | cnt: M | partials: 16
    char* ws = (char*)d_ws;
    unsigned short* S  = (unsigned short*)ws;
    unsigned short* Wt = (unsigned short*)(ws + (size_t)M * D_OUT * 2);
    unsigned long long* edges = (unsigned long long*)((char*)Wt + (size_t)D_OUT * D_IN * 2);
    int*  ptr          = (int*)((char*)edges + (size_t)E * 8);
    int*  cnt          = ptr + ((M + 4) & ~3);
    int*  partials     = cnt + M;      // contiguous after cnt -> zeroed together

    // 1) W -> bf16 transposed, fused with cnt+partials zeroing
    int NZ = M + 16;
    convert_and_zero<<<CONV_BLOCKS + (NZ + 511) / 512, 512, 0, stream>>>(weights, Wt, cnt, NZ);

    // 2) CSR histogram + single-dispatch global scan (decoupled lookback)
    hist_rows<<<(E + 1023) / 1024, 256, 0, stream>>>(edge_row, cnt, E);
    scan_blocks<<<(M + SCAN_B - 1) / SCAN_B, 1024, 0, stream>>>(cnt, ptr, partials, M);

    // 3) B-resident barrier-free GEMM + in-block destructive edge placement
    gemm_build<<<dim3(128, 2), 576, 0, stream>>>(inputs, Wt, S, M,
                                                 edge_vals, edge_row, edge_col,
                                                 ptr, edges, E);

    // 4) aggregate (shifted CSR bounds)
    spmm_rows<<<(M + 3) / 4, 256, 0, stream>>>(S, (const int2*)edges, ptr, bias, out, M);
}

// Round 6
// 391.107 us; speedup vs baseline: 1.4321x; 1.4321x over previous
//
#include <hip/hip_runtime.h>

#define D_IN 512
#define D_OUT 256
#define BM 64     // gemm M-tile
#define BN 256    // full D_OUT: A is read from HBM exactly once
#define BK 32

typedef short short8 __attribute__((ext_vector_type(8)));
typedef float floatx4 __attribute__((ext_vector_type(4)));

static __device__ __forceinline__ unsigned short f2bf(float f) {
    unsigned u = __float_as_uint(f);
    u += 0x7FFF + ((u >> 16) & 1);
    return (unsigned short)(u >> 16);
}
static __device__ __forceinline__ float bf2f(unsigned short h) {
    return __uint_as_float((unsigned)h << 16);
}

// ---------------- fused: W convert+transpose + cnt/partials/flag zeroing ----------
#define CONV_BLOCKS 256
__global__ __launch_bounds__(512) void convert_and_zero(const float* __restrict__ W,
                                                        unsigned short* __restrict__ Wt,
                                                        int* __restrict__ cnt, int NZ) {
    int b = blockIdx.x;
    if (b < CONV_BLOCKS) {
        int t = b * 512 + threadIdx.x;     // D_IN*D_OUT = 131072 = 256*512
        int n = t >> 9;
        int k = t & 511;
        Wt[t] = f2bf(W[(size_t)k * D_OUT + n]);
    } else {
        int i = (b - CONV_BLOCKS) * 512 + threadIdx.x;
        if (i < NZ) cnt[i] = 0;
    }
}

// ---------------- fused hist + scan (one dispatch, 404 co-resident blocks) --------
// blocks [0, NH): histogram 4096 edges each (4/thread, int4), then publish to
//   histdone (device-scope atomic) after a fence.
// blocks [NH, NH+13): spin until histdone == NH, then block-local scan with
//   decoupled lookback across scan blocks (partials value|READY — validated R4/R5).
#define SCAN_B 4096
#define SCAN_READY (1 << 30)
__global__ __launch_bounds__(1024) void hist_scan(const int* __restrict__ rows,
                                                  int* __restrict__ cnt,
                                                  int* __restrict__ ptr,
                                                  int* __restrict__ partials,
                                                  int* __restrict__ histdone,
                                                  int M, int E, int NH) {
    const int t = threadIdx.x;
    const int bid = blockIdx.x;

    if (bid < NH) {
        // ---- hist role ----
        int e0 = bid * 4096 + t * 4;
        if (e0 + 3 < E) {
            int4 r = *(const int4*)(rows + e0);
            atomicAdd(&cnt[r.x], 1);
            atomicAdd(&cnt[r.y], 1);
            atomicAdd(&cnt[r.z], 1);
            atomicAdd(&cnt[r.w], 1);
        } else {
            for (int e = e0; e < E; ++e) atomicAdd(&cnt[rows[e]], 1);
        }
        __threadfence();
        __syncthreads();
        if (t == 0) atomicAdd(histdone, 1);
        return;
    }

    // ---- scan role ----
    if (t == 0) {
        while (atomicAdd(histdone, 0) != NH) { }
    }
    __syncthreads();
    __threadfence();

    __shared__ int wsum[16];
    __shared__ int s_off;
    const int sb = bid - NH;
    const int lane = t & 63, wave = t >> 6;
    const int base = sb * SCAN_B + t * 4;
    int4 v = make_int4(0, 0, 0, 0);
    if (base + 3 < M) v = *(const int4*)(cnt + base);
    else {
        if (base + 0 < M) v.x = cnt[base + 0];
        if (base + 1 < M) v.y = cnt[base + 1];
        if (base + 2 < M) v.z = cnt[base + 2];
        if (base + 3 < M) v.w = cnt[base + 3];
    }
    int s = v.x + v.y + v.z + v.w;
    int incl = s;
#pragma unroll
    for (int off = 1; off < 64; off <<= 1) {
        int x = __shfl_up(incl, off, 64);
        if (lane >= off) incl += x;
    }
    if (lane == 63) wsum[wave] = incl;
    __syncthreads();
    if (t == 0) {
        int run = 0;
#pragma unroll
        for (int w = 0; w < 16; ++w) { int x = wsum[w]; wsum[w] = run; run += x; }
        atomicExch(&partials[sb], run | SCAN_READY);
        int off = 0;
        for (int j = 0; j < sb; ++j) {
            int pv;
            do { pv = atomicAdd(&partials[j], 0); } while (!(pv & SCAN_READY));
            off += pv & ~SCAN_READY;
        }
        s_off = off;
    }
    __syncthreads();
    int g = s_off + wsum[wave] + (incl - s);
    int e0 = g, e1 = e0 + v.x, e2 = e1 + v.y, e3 = e2 + v.z;
    if (base + 3 < M) *(int4*)(ptr + base) = make_int4(e0, e1, e2, e3);
    else {
        if (base + 0 < M) ptr[base + 0] = e0;
        if (base + 1 < M) ptr[base + 1] = e1;
        if (base + 2 < M) ptr[base + 2] = e2;
        if (base + 3 < M) ptr[base + 3] = e3;
    }
}

// ---------------- fused: GEMM (blocks [0,nGemm)) + edge placement (tail) ---------
// R1's proven schedule (86.8 us): BM=64 x BN=256, BK=32, depth-1 register
// prefetch, gemm-first / build-tail. ONLY change vs R1: k-plane LDS layout
// [p][row][8] (R4-verified: SQ_LDS_BANK_CONFLICT = 0 with this exact staging).
__global__ __launch_bounds__(512, 4) void gemm_build(
    const float* __restrict__ A, const unsigned short* __restrict__ Wt,
    unsigned short* __restrict__ S, int M, int nGemm,
    const float* __restrict__ vals, const int* __restrict__ rows,
    const int* __restrict__ cols, int* __restrict__ ptr,
    unsigned long long* __restrict__ edges, int E) {
    __shared__ unsigned short As[4 * BM * 8];   // 4 KB
    __shared__ unsigned short Bs[4 * BN * 8];   // 16 KB
    const int bid = blockIdx.x;
    const int tid = threadIdx.x;

    if (bid >= nGemm) {
        // ---- build role (tail): 2048 edges (4 consecutive/thread), destructive ----
        int e0 = (bid - nGemm) * 2048 + tid * 4;
        if (e0 + 3 < E) {
            int4   rr = *(const int4*)(rows + e0);
            int4   cc = *(const int4*)(cols + e0);
            float4 vv = *(const float4*)(vals + e0);
            int p0 = atomicAdd(&ptr[rr.x], 1);
            __builtin_nontemporal_store(
                (unsigned long long)(unsigned)cc.x |
                ((unsigned long long)(unsigned)__float_as_int(vv.x) << 32), edges + p0);
            int p1 = atomicAdd(&ptr[rr.y], 1);
            __builtin_nontemporal_store(
                (unsigned long long)(unsigned)cc.y |
                ((unsigned long long)(unsigned)__float_as_int(vv.y) << 32), edges + p1);
            int p2 = atomicAdd(&ptr[rr.z], 1);
            __builtin_nontemporal_store(
                (unsigned long long)(unsigned)cc.z |
                ((unsigned long long)(unsigned)__float_as_int(vv.z) << 32), edges + p2);
            int p3 = atomicAdd(&ptr[rr.w], 1);
            __builtin_nontemporal_store(
                (unsigned long long)(unsigned)cc.w |
                ((unsigned long long)(unsigned)__float_as_int(vv.w) << 32), edges + p3);
        } else {
            for (int e = e0; e < E; ++e) {
                int pos = atomicAdd(&ptr[rows[e]], 1);
                unsigned long long packed =
                    (unsigned long long)(unsigned)cols[e] |
                    ((unsigned long long)(unsigned)__float_as_int(vals[e]) << 32);
                __builtin_nontemporal_store(packed, edges + pos);
            }
        }
        return;
    }

    // ---- gemm role ----
    const int bm   = bid * BM;
    const int lane = tid & 63;
    const int wave = tid >> 6;
    const int l15  = lane & 15;
    const int quad = lane >> 4;      // 0..3
    const int wn   = wave * 32;      // 8 waves cover 256 cols

    // A staging (threads 0..255): 1 chunk (16B LDS / 32B global) at (plane, row)
    const bool isA  = tid < 256;
    const int  arow = tid & 63;
    const int  apl  = (tid >> 6) & 3;
    const bool aval = isA && (bm + arow) < M;
    const float* aptr = A + (size_t)(aval ? bm + arow : 0) * D_IN + apl * 8;
    const int awoff = (apl * BM + arow) * 8;

    // B staging (all 512): 2 chunks/thread at (plane bp0 / bp0+2, row brow)
    const int brow = tid & 255;
    const int bp0  = tid >> 8;                    // 0..1
    const unsigned short* bptr0 = Wt + (size_t)brow * D_IN + bp0 * 8;
    const unsigned short* bptr1 = Wt + (size_t)brow * D_IN + (bp0 + 2) * 8;
    const int bwoff0 = (bp0 * BN + brow) * 8;
    const int bwoff1 = ((bp0 + 2) * BN + brow) * 8;

    // prologue: K-tile 0 into registers (depth-1, R1 schedule)
    const float4 fz = make_float4(0.f, 0.f, 0.f, 0.f);
    float4 aR0 = aval ? *(const float4*)(aptr + 0) : fz;
    float4 aR1 = aval ? *(const float4*)(aptr + 4) : fz;
    short8 bR0 = *(const short8*)bptr0;
    short8 bR1 = *(const short8*)bptr1;

    floatx4 acc[4][2] = {};

    for (int k0 = 0; k0 < D_IN; k0 += BK) {
        // drain staged regs -> LDS (A converted to bf16)
        if (isA) {
            short8 a8;
            a8[0] = (short)f2bf(aR0.x); a8[1] = (short)f2bf(aR0.y);
            a8[2] = (short)f2bf(aR0.z); a8[3] = (short)f2bf(aR0.w);
            a8[4] = (short)f2bf(aR1.x); a8[5] = (short)f2bf(aR1.y);
            a8[6] = (short)f2bf(aR1.z); a8[7] = (short)f2bf(aR1.w);
            *(short8*)(As + awoff) = a8;
        }
        *(short8*)(Bs + bwoff0) = bR0;
        *(short8*)(Bs + bwoff1) = bR1;
        __syncthreads();

        // prefetch next K-tile (hides under frag reads + MFMA + barrier)
        if (k0 + BK < D_IN) {
            aR0 = aval ? *(const float4*)(aptr + k0 + BK + 0) : fz;
            aR1 = aval ? *(const float4*)(aptr + k0 + BK + 4) : fz;
            bR0 = *(const short8*)(bptr0 + k0 + BK);
            bR1 = *(const short8*)(bptr1 + k0 + BK);
        }

        short8 af[4], bfr[2];
#pragma unroll
        for (int i = 0; i < 4; ++i)
            af[i] = *(const short8*)(As + (quad * BM + i * 16 + l15) * 8);
#pragma unroll
        for (int j = 0; j < 2; ++j)
            bfr[j] = *(const short8*)(Bs + (quad * BN + wn + j * 16 + l15) * 8);
#pragma unroll
        for (int i = 0; i < 4; ++i)
#pragma unroll
            for (int j = 0; j < 2; ++j)
                acc[i][j] = __builtin_amdgcn_mfma_f32_16x16x32_bf16(
                    af[i], bfr[j], acc[i][j], 0, 0, 0);
        __syncthreads();
    }

    // epilogue: row = bm+i*16+quad*4+r, col = wn+j*16+l15
#pragma unroll
    for (int i = 0; i < 4; ++i) {
#pragma unroll
        for (int r = 0; r < 4; ++r) {
            int gm = bm + i * 16 + quad * 4 + r;
            if (gm < M) {
#pragma unroll
                for (int j = 0; j < 2; ++j)
                    S[(size_t)gm * D_OUT + wn + j * 16 + l15] = f2bf(acc[i][j][r]);
            }
        }
    }
}

// ---------------- Aggregate: one wave/row, 8-edge unroll, fp32 accum ----------------
// Reads shifted (destructive) CSR: row extent = [row ? ptr[row-1] : 0, ptr[row]).
__global__ __launch_bounds__(256) void spmm_rows(const unsigned short* __restrict__ S,
                                                 const int2* __restrict__ edges,
                                                 const int* __restrict__ ptr,
                                                 const float* __restrict__ bias,
                                                 float* __restrict__ out, int M) {
    const int row = blockIdx.x * 4 + (threadIdx.x >> 6);
    if (row >= M) return;
    const int lane = threadIdx.x & 63;
    float4 a0 = ((const float4*)bias)[lane];
    float4 a1 = make_float4(0.f, 0.f, 0.f, 0.f);
    const int beg = row ? ptr[row - 1] : 0;
    const int end = ptr[row];
    int j = beg;
    for (; j + 7 < end; j += 8) {
        int2 e0 = edges[j + 0], e1 = edges[j + 1], e2 = edges[j + 2], e3 = edges[j + 3];
        int2 e4 = edges[j + 4], e5 = edges[j + 5], e6 = edges[j + 6], e7 = edges[j + 7];
        ushort4 s0 = ((const ushort4*)(S + (size_t)e0.x * D_OUT))[lane];
        ushort4 s1 = ((const ushort4*)(S + (size_t)e1.x * D_OUT))[lane];
        ushort4 s2 = ((const ushort4*)(S + (size_t)e2.x * D_OUT))[lane];
        ushort4 s3 = ((const ushort4*)(S + (size_t)e3.x * D_OUT))[lane];
        ushort4 s4 = ((const ushort4*)(S + (size_t)e4.x * D_OUT))[lane];
        ushort4 s5 = ((const ushort4*)(S + (size_t)e5.x * D_OUT))[lane];
        ushort4 s6 = ((const ushort4*)(S + (size_t)e6.x * D_OUT))[lane];
        ushort4 s7 = ((const ushort4*)(S + (size_t)e7.x * D_OUT))[lane];
        float v0 = __int_as_float(e0.y), v1 = __int_as_float(e1.y);
        float v2 = __int_as_float(e2.y), v3 = __int_as_float(e3.y);
        float v4 = __int_as_float(e4.y), v5 = __int_as_float(e5.y);
        float v6 = __int_as_float(e6.y), v7 = __int_as_float(e7.y);
        a0.x += v0 * bf2f(s0.x) + v2 * bf2f(s2.x) + v4 * bf2f(s4.x) + v6 * bf2f(s6.x);
        a0.y += v0 * bf2f(s0.y) + v2 * bf2f(s2.y) + v4 * bf2f(s4.y) + v6 * bf2f(s6.y);
        a0.z += v0 * bf2f(s0.z) + v2 * bf2f(s2.z) + v4 * bf2f(s4.z) + v6 * bf2f(s6.z);
        a0.w += v0 * bf2f(s0.w) + v2 * bf2f(s2.w) + v4 * bf2f(s4.w) + v6 * bf2f(s6.w);
        a1.x += v1 * bf2f(s1.x) + v3 * bf2f(s3.x) + v5 * bf2f(s5.x) + v7 * bf2f(s7.x);
        a1.y += v1 * bf2f(s1.y) + v3 * bf2f(s3.y) + v5 * bf2f(s5.y) + v7 * bf2f(s7.y);
        a1.z += v1 * bf2f(s1.z) + v3 * bf2f(s3.z) + v5 * bf2f(s5.z) + v7 * bf2f(s7.z);
        a1.w += v1 * bf2f(s1.w) + v3 * bf2f(s3.w) + v5 * bf2f(s5.w) + v7 * bf2f(s7.w);
    }
    for (; j + 3 < end; j += 4) {
        int2 e0 = edges[j], e1 = edges[j + 1], e2 = edges[j + 2], e3 = edges[j + 3];
        ushort4 s0 = ((const ushort4*)(S + (size_t)e0.x * D_OUT))[lane];
        ushort4 s1 = ((const ushort4*)(S + (size_t)e1.x * D_OUT))[lane];
        ushort4 s2 = ((const ushort4*)(S + (size_t)e2.x * D_OUT))[lane];
        ushort4 s3 = ((const ushort4*)(S + (size_t)e3.x * D_OUT))[lane];
        float v0 = __int_as_float(e0.y), v1 = __int_as_float(e1.y);
        float v2 = __int_as_float(e2.y), v3 = __int_as_float(e3.y);
        a0.x += v0 * bf2f(s0.x) + v2 * bf2f(s2.x);
        a0.y += v0 * bf2f(s0.y) + v2 * bf2f(s2.y);
        a0.z += v0 * bf2f(s0.z) + v2 * bf2f(s2.z);
        a0.w += v0 * bf2f(s0.w) + v2 * bf2f(s2.w);
        a1.x += v1 * bf2f(s1.x) + v3 * bf2f(s3.x);
        a1.y += v1 * bf2f(s1.y) + v3 * bf2f(s3.y);
        a1.z += v1 * bf2f(s1.z) + v3 * bf2f(s3.z);
        a1.w += v1 * bf2f(s1.w) + v3 * bf2f(s3.w);
    }
    for (; j < end; ++j) {
        int2 e = edges[j];
        float v = __int_as_float(e.y);
        ushort4 s = ((const ushort4*)(S + (size_t)e.x * D_OUT))[lane];
        a0.x += v * bf2f(s.x);
        a0.y += v * bf2f(s.y);
        a0.z += v * bf2f(s.z);
        a0.w += v * bf2f(s.w);
    }
    a0.x += a1.x; a0.y += a1.y; a0.z += a1.z; a0.w += a1.w;
    floatx4 res = {a0.x, a0.y, a0.z, a0.w};
    __builtin_nontemporal_store(res, (floatx4*)(out + (size_t)row * D_OUT) + lane);
}

extern "C" void kernel_launch(void* const* d_in, const int* in_sizes, int n_in,
                              void* d_out, int out_size, void* d_ws, size_t ws_size,
                              hipStream_t stream) {
    const float* inputs    = (const float*)d_in[0];
    const float* weights   = (const float*)d_in[1];
    const float* bias      = (const float*)d_in[2];
    const float* edge_vals = (const float*)d_in[3];
    const int*   edge_row  = (const int*)d_in[4];
    const int*   edge_col  = (const int*)d_in[5];
    float* out = (float*)d_out;

    const int M = in_sizes[0] / D_IN;  // 50000
    const int E = in_sizes[3];         // 800000

    // Workspace:
    //   S: M*D_OUT bf16 | Wt: D_OUT*D_IN bf16 | edges: E u64 | ptr | cnt | partials | flag
    char* ws = (char*)d_ws;
    unsigned short* S  = (unsigned short*)ws;
    unsigned short* Wt = (unsigned short*)(ws + (size_t)M * D_OUT * 2);
    unsigned long long* edges = (unsigned long long*)((char*)Wt + (size_t)D_OUT * D_IN * 2);
    int*  ptr          = (int*)((char*)edges + (size_t)E * 8);
    int*  cnt          = ptr + ((M + 4) & ~3);
    int*  partials     = cnt + M;      // 16 ints
    int*  histdone     = partials + 16;

    // 1) W -> bf16 transposed, fused with cnt+partials+flag zeroing
    int NZ = M + 32;
    convert_and_zero<<<CONV_BLOCKS + (NZ + 511) / 512, 512, 0, stream>>>(weights, Wt, cnt, NZ);

    // 2) fused histogram + global scan (196 hist blocks + 13 scan blocks, all
    //    co-resident; scan spins on device-scope histdone counter)
    int NH = (E + 4095) / 4096;        // 196
    int NS = (M + SCAN_B - 1) / SCAN_B;  // 13
    hist_scan<<<NH + NS, 1024, 0, stream>>>(edge_row, cnt, ptr, partials, histdone,
                                            M, E, NH);

    // 3) GEMM (first 782 blocks) + destructive edge placement (tail 391 blocks)
    int nGemm  = (M + BM - 1) / BM;       // 782
    int nBuild = (E + 2047) / 2048;       // 391
    gemm_build<<<nGemm + nBuild, 512, 0, stream>>>(inputs, Wt, S, M, nGemm,
                                                   edge_vals, edge_row, edge_col,
                                                   ptr, edges, E);

    // 4) aggregate (shifted CSR bounds)
    spmm_rows<<<(M + 3) / 4, 256, 0, stream>>>(S, (const int2*)edges, ptr, bias, out, M);
}

// Round 8
// 349.628 us; speedup vs baseline: 1.6020x; 1.1186x over previous
//
#include <hip/hip_runtime.h>

#define D_IN 512
#define D_OUT 256
#define BK 32

typedef short short8 __attribute__((ext_vector_type(8)));
typedef float floatx4 __attribute__((ext_vector_type(4)));
typedef unsigned int u32;

static __device__ __forceinline__ unsigned short f2bf(float f) {
    unsigned u = __float_as_uint(f);
    u += 0x7FFF + ((u >> 16) & 1);
    return (unsigned short)(u >> 16);
}
static __device__ __forceinline__ float bf2f(unsigned short h) {
    return __uint_as_float((unsigned)h << 16);
}

// async global->LDS, 16B per lane (m97 staging primitive).
// LDS dest is wave-uniform base + lane*16 (lane-contiguous chunks); global src per-lane.
static __device__ __forceinline__ void gload16(const void* g, void* l) {
    __builtin_amdgcn_global_load_lds(
        (const __attribute__((address_space(1))) u32*)g,
        (__attribute__((address_space(3))) u32*)l, 16, 0, 0);
}

// ---------------- prep: optional A->bf16 (padded rows zero-filled) + W + zeroing ---
// blocks [0, NA): A16[e] = bf16(A[e]) (8 elems/thread).  NA==0 on fallback path.
// blocks [NA, NA+256): Wt[n][k] = bf16(W[k][n])
// blocks [NA+256, ...): zero cnt[M] + partials/flags
__global__ __launch_bounds__(512) void prep(const float* __restrict__ A,
                                            unsigned short* __restrict__ A16,
                                            const float* __restrict__ W,
                                            unsigned short* __restrict__ Wt,
                                            int* __restrict__ cnt,
                                            int M, int NA, int NZ) {
    int b = blockIdx.x;
    if (b < NA) {
        size_t e = (size_t)b * 4096 + threadIdx.x * 8;   // 8 elems, same row (8|512)
        int row = (int)(e >> 9);
        short8 o;
        if (row < M) {
            float4 lo = *(const float4*)(A + e);
            float4 hi = *(const float4*)(A + e + 4);
            o[0] = (short)f2bf(lo.x); o[1] = (short)f2bf(lo.y);
            o[2] = (short)f2bf(lo.z); o[3] = (short)f2bf(lo.w);
            o[4] = (short)f2bf(hi.x); o[5] = (short)f2bf(hi.y);
            o[6] = (short)f2bf(hi.z); o[7] = (short)f2bf(hi.w);
        } else {
            o = (short8){0, 0, 0, 0, 0, 0, 0, 0};
        }
        *(short8*)(A16 + e) = o;
    } else if (b < NA + 256) {
        int t = (b - NA) * 512 + threadIdx.x;   // 131072 = 256*512
        int n = t >> 9;
        int k = t & 511;
        Wt[t] = f2bf(W[(size_t)k * D_OUT + n]);
    } else {
        int i = (b - NA - 256) * 512 + threadIdx.x;
        if (i < NZ) cnt[i] = 0;
    }
}

// ---------------- CSR histogram (4 edges/thread) ----------------
__global__ __launch_bounds__(256) void hist_rows(const int* __restrict__ rows,
                                                 int* __restrict__ cnt, int E) {
    int e0 = (blockIdx.x * 256 + threadIdx.x) * 4;
    if (e0 + 3 < E) {
        int4 r = *(const int4*)(rows + e0);
        atomicAdd(&cnt[r.x], 1);
        atomicAdd(&cnt[r.y], 1);
        atomicAdd(&cnt[r.z], 1);
        atomicAdd(&cnt[r.w], 1);
    } else {
        for (int e = e0; e < E; ++e) atomicAdd(&cnt[rows[e]], 1);
    }
}

// ---------------- single-dispatch scan, decoupled lookback (validated R4-R6) ------
#define SCAN_B 4096
#define SCAN_READY (1 << 30)
__global__ __launch_bounds__(1024) void scan_blocks(const int* __restrict__ cnt,
                                                    int* __restrict__ ptr,
                                                    int* __restrict__ partials, int M) {
    __shared__ int wsum[16];
    __shared__ int s_off;
    const int t = threadIdx.x, lane = t & 63, wave = t >> 6;
    const int base = blockIdx.x * SCAN_B + t * 4;
    int4 v = make_int4(0, 0, 0, 0);
    if (base + 3 < M) v = *(const int4*)(cnt + base);
    else {
        if (base + 0 < M) v.x = cnt[base + 0];
        if (base + 1 < M) v.y = cnt[base + 1];
        if (base + 2 < M) v.z = cnt[base + 2];
        if (base + 3 < M) v.w = cnt[base + 3];
    }
    int s = v.x + v.y + v.z + v.w;
    int incl = s;
#pragma unroll
    for (int off = 1; off < 64; off <<= 1) {
        int x = __shfl_up(incl, off, 64);
        if (lane >= off) incl += x;
    }
    if (lane == 63) wsum[wave] = incl;
    __syncthreads();
    if (t == 0) {
        int run = 0;
#pragma unroll
        for (int w = 0; w < 16; ++w) { int x = wsum[w]; wsum[w] = run; run += x; }
        atomicExch(&partials[blockIdx.x], run | SCAN_READY);
        int off = 0;
        for (int j = 0; j < (int)blockIdx.x; ++j) {
            int pv;
            do { pv = atomicAdd(&partials[j], 0); } while (!(pv & SCAN_READY));
            off += pv & ~SCAN_READY;
        }
        s_off = off;
    }
    __syncthreads();
    int g = s_off + wsum[wave] + (incl - s);
    int e0 = g, e1 = e0 + v.x, e2 = e1 + v.y, e3 = e2 + v.z;
    if (base + 3 < M) *(int4*)(ptr + base) = make_int4(e0, e1, e2, e3);
    else {
        if (base + 0 < M) ptr[base + 0] = e0;
        if (base + 1 < M) ptr[base + 1] = e1;
        if (base + 2 < M) ptr[base + 2] = e2;
        if (base + 3 < M) ptr[base + 3] = e3;
    }
}

// ---------------- MAIN PATH: m97-style GEMM (global_load_lds) + R1 build tail -----
// GEMM blocks [0, nGemm): S = A16 @ Wt, tile 128x128, 512 thr (8 waves 2Mx4N).
// LDS 16 KB: A [p][row][8] (4096 elems) | B [p][col][8] (4096). Staging = 2x
// global_load_lds(16B)/thread/step (lane-contiguous dest chunks), frag reads
// are 16 contiguous 16B chunks per quarter-wave: conflict-free both sides
// (k-plane pattern, PMC-verified 0 conflicts in R2/R4/R6).
// acc[4][2] (~90 VGPR) fits __launch_bounds__(512,4) without spill.
// Build blocks [nGemm, ...): R1's exact 512-edges/block destructive placement.
__global__ __launch_bounds__(512, 4) void gemm_build_lds(
    const unsigned short* __restrict__ A16, const unsigned short* __restrict__ Wt,
    unsigned short* __restrict__ S, int M, int nGemm,
    const float* __restrict__ vals, const int* __restrict__ rows,
    const int* __restrict__ cols, int* __restrict__ ptr,
    int2* __restrict__ edges, int E) {
    __shared__ unsigned short lds[8192];   // A: 4096 elems | B: 4096 elems (16 KB)
    const int bid = blockIdx.x;
    const int tid = threadIdx.x;

    if (bid >= nGemm) {
        int e = (bid - nGemm) * 512 + tid;
        if (e < E) {
            int r = rows[e];
            int pos = atomicAdd(&ptr[r], 1);
            edges[pos] = make_int2(cols[e], __float_as_int(vals[e]));
        }
        return;
    }

    const int bm   = (bid >> 1) * 128;
    const int bn   = (bid & 1) * 128;
    const int lane = tid & 63;
    const int wave = tid >> 6;
    const int l15  = lane & 15;
    const int quad = lane >> 4;
    const int wm   = (wave >> 2) * 64;
    const int wn   = (wave & 3) * 32;

    // staging: chunk c = tid; p = tid>>7 (0..3), row/col = tid&127
    const unsigned short* aSrc = A16 + (size_t)(bm + (tid & 127)) * D_IN + (tid >> 7) * 8;
    const unsigned short* bSrc = Wt  + (size_t)(bn + (tid & 127)) * D_IN + (tid >> 7) * 8;
    unsigned short* aDst = lds + tid * 8;
    unsigned short* bDst = lds + 4096 + tid * 8;

    floatx4 acc[4][2] = {};

#define STAGE(K0) { gload16(aSrc + (K0), aDst); gload16(bSrc + (K0), bDst); }

    STAGE(0);
#pragma unroll
    for (int t = 0; t < 16; ++t) {
        __syncthreads();   // compiler drains vmcnt(0): staged tile t visible

        short8 af[4], bfr[2];
#pragma unroll
        for (int i = 0; i < 4; ++i)
            af[i] = *(const short8*)(lds + (quad * 128 + wm + i * 16 + l15) * 8);
#pragma unroll
        for (int j = 0; j < 2; ++j)
            bfr[j] = *(const short8*)(lds + 4096 + (quad * 128 + wn + j * 16 + l15) * 8);
#pragma unroll
        for (int i = 0; i < 4; ++i)
#pragma unroll
            for (int j = 0; j < 2; ++j)
                acc[i][j] = __builtin_amdgcn_mfma_f32_16x16x32_bf16(
                    af[i], bfr[j], acc[i][j], 0, 0, 0);

        __syncthreads();   // all waves done reading tile t
        if (t < 15) STAGE((t + 1) * BK);
    }
#undef STAGE

    // epilogue: row = bm+wm+i*16+quad*4+r, col = bn+wn+j*16+l15
#pragma unroll
    for (int i = 0; i < 4; ++i) {
#pragma unroll
        for (int r = 0; r < 4; ++r) {
            int gm = bm + wm + i * 16 + quad * 4 + r;
            if (gm < M) {
#pragma unroll
                for (int j = 0; j < 2; ++j)
                    S[(size_t)gm * D_OUT + bn + wn + j * 16 + l15] = f2bf(acc[i][j][r]);
            }
        }
    }
}

// ---------------- FALLBACK PATH: R1's exact register-staged GEMM (86.8 us) --------
#define LDK 40
__global__ __launch_bounds__(512, 4) void gemm_build_reg(
    const float* __restrict__ A, const unsigned short* __restrict__ Wt,
    unsigned short* __restrict__ S, int M, int nGemm,
    const float* __restrict__ vals, const int* __restrict__ rows,
    const int* __restrict__ cols, int* __restrict__ ptr,
    int2* __restrict__ edges, int E) {
    __shared__ unsigned short As[64 * LDK];
    __shared__ unsigned short Bs[256 * LDK];
    const int tid = threadIdx.x;

    if ((int)blockIdx.x >= nGemm) {
        int e = ((int)blockIdx.x - nGemm) * 512 + tid;
        if (e < E) {
            int r = rows[e];
            int pos = atomicAdd(&ptr[r], 1);
            edges[pos] = make_int2(cols[e], __float_as_int(vals[e]));
        }
        return;
    }

    const int lane = tid & 63;
    const int wave = tid >> 6;
    const int wn   = wave * 32;
    const int bm   = blockIdx.x * 64;
    const int l15  = lane & 15;
    const int quad = lane >> 4;

    const int am   = tid >> 3;
    const int ak4  = (tid & 7) * 4;
    const bool aval = (bm + am) < M;
    const float* aptr = A + (size_t)(aval ? bm + am : 0) * D_IN + ak4;
    const int aoff = am * LDK + ak4;

    const unsigned short* bptr[2];
    int boff[2];
#pragma unroll
    for (int i = 0; i < 2; ++i) {
        int item = tid + i * 512;
        int bn = item >> 2;
        int k8 = (item & 3) * 8;
        bptr[i] = Wt + (size_t)bn * D_IN + k8;
        boff[i] = bn * LDK + k8;
    }

    float4 aR = aval ? *(const float4*)aptr : make_float4(0.f, 0.f, 0.f, 0.f);
    short8 bR[2];
#pragma unroll
    for (int i = 0; i < 2; ++i) bR[i] = *(const short8*)(bptr[i]);

    floatx4 acc[4][2] = {};

    for (int k0 = 0; k0 < D_IN; k0 += BK) {
        ushort4 ab;
        ab.x = f2bf(aR.x); ab.y = f2bf(aR.y); ab.z = f2bf(aR.z); ab.w = f2bf(aR.w);
        *(ushort4*)(As + aoff) = ab;
#pragma unroll
        for (int i = 0; i < 2; ++i) *(short8*)(Bs + boff[i]) = bR[i];
        __syncthreads();

        if (k0 + BK < D_IN) {
            aR = aval ? *(const float4*)(aptr + k0 + BK)
                      : make_float4(0.f, 0.f, 0.f, 0.f);
#pragma unroll
            for (int i = 0; i < 2; ++i) bR[i] = *(const short8*)(bptr[i] + k0 + BK);
        }

        short8 af[4], bfr[2];
#pragma unroll
        for (int i = 0; i < 4; ++i)
            af[i] = *(const short8*)(As + (i * 16 + l15) * LDK + quad * 8);
#pragma unroll
        for (int j = 0; j < 2; ++j)
            bfr[j] = *(const short8*)(Bs + (wn + j * 16 + l15) * LDK + quad * 8);
#pragma unroll
        for (int i = 0; i < 4; ++i)
#pragma unroll
            for (int j = 0; j < 2; ++j)
                acc[i][j] = __builtin_amdgcn_mfma_f32_16x16x32_bf16(
                    af[i], bfr[j], acc[i][j], 0, 0, 0);
        __syncthreads();
    }

#pragma unroll
    for (int i = 0; i < 4; ++i) {
#pragma unroll
        for (int r = 0; r < 4; ++r) {
            int gm = bm + i * 16 + quad * 4 + r;
            if (gm < M) {
#pragma unroll
                for (int j = 0; j < 2; ++j)
                    S[(size_t)gm * D_OUT + wn + j * 16 + l15] = f2bf(acc[i][j][r]);
            }
        }
    }
}

// ---------------- Aggregate: one wave/row, 8-edge unroll, fp32 accum ----------------
// Reads shifted (destructive) CSR: row extent = [row ? ptr[row-1] : 0, ptr[row]).
__global__ __launch_bounds__(256) void spmm_rows(const unsigned short* __restrict__ S,
                                                 const int2* __restrict__ edges,
                                                 const int* __restrict__ ptr,
                                                 const float* __restrict__ bias,
                                                 float* __restrict__ out, int M) {
    const int row = blockIdx.x * 4 + (threadIdx.x >> 6);
    if (row >= M) return;
    const int lane = threadIdx.x & 63;
    float4 a0 = ((const float4*)bias)[lane];
    float4 a1 = make_float4(0.f, 0.f, 0.f, 0.f);
    const int beg = row ? ptr[row - 1] : 0;
    const int end = ptr[row];
    int j = beg;
    for (; j + 7 < end; j += 8) {
        int2 e0 = edges[j + 0], e1 = edges[j + 1], e2 = edges[j + 2], e3 = edges[j + 3];
        int2 e4 = edges[j + 4], e5 = edges[j + 5], e6 = edges[j + 6], e7 = edges[j + 7];
        ushort4 s0 = ((const ushort4*)(S + (size_t)e0.x * D_OUT))[lane];
        ushort4 s1 = ((const ushort4*)(S + (size_t)e1.x * D_OUT))[lane];
        ushort4 s2 = ((const ushort4*)(S + (size_t)e2.x * D_OUT))[lane];
        ushort4 s3 = ((const ushort4*)(S + (size_t)e3.x * D_OUT))[lane];
        ushort4 s4 = ((const ushort4*)(S + (size_t)e4.x * D_OUT))[lane];
        ushort4 s5 = ((const ushort4*)(S + (size_t)e5.x * D_OUT))[lane];
        ushort4 s6 = ((const ushort4*)(S + (size_t)e6.x * D_OUT))[lane];
        ushort4 s7 = ((const ushort4*)(S + (size_t)e7.x * D_OUT))[lane];
        float v0 = __int_as_float(e0.y), v1 = __int_as_float(e1.y);
        float v2 = __int_as_float(e2.y), v3 = __int_as_float(e3.y);
        float v4 = __int_as_float(e4.y), v5 = __int_as_float(e5.y);
        float v6 = __int_as_float(e6.y), v7 = __int_as_float(e7.y);
        a0.x += v0 * bf2f(s0.x) + v2 * bf2f(s2.x) + v4 * bf2f(s4.x) + v6 * bf2f(s6.x);
        a0.y += v0 * bf2f(s0.y) + v2 * bf2f(s2.y) + v4 * bf2f(s4.y) + v6 * bf2f(s6.y);
        a0.z += v0 * bf2f(s0.z) + v2 * bf2f(s2.z) + v4 * bf2f(s4.z) + v6 * bf2f(s6.z);
        a0.w += v0 * bf2f(s0.w) + v2 * bf2f(s2.w) + v4 * bf2f(s4.w) + v6 * bf2f(s6.w);
        a1.x += v1 * bf2f(s1.x) + v3 * bf2f(s3.x) + v5 * bf2f(s5.x) + v7 * bf2f(s7.x);
        a1.y += v1 * bf2f(s1.y) + v3 * bf2f(s3.y) + v5 * bf2f(s5.y) + v7 * bf2f(s7.y);
        a1.z += v1 * bf2f(s1.z) + v3 * bf2f(s3.z) + v5 * bf2f(s5.z) + v7 * bf2f(s7.z);
        a1.w += v1 * bf2f(s1.w) + v3 * bf2f(s3.w) + v5 * bf2f(s5.w) + v7 * bf2f(s7.w);
    }
    for (; j + 3 < end; j += 4) {
        int2 e0 = edges[j], e1 = edges[j + 1], e2 = edges[j + 2], e3 = edges[j + 3];
        ushort4 s0 = ((const ushort4*)(S + (size_t)e0.x * D_OUT))[lane];
        ushort4 s1 = ((const ushort4*)(S + (size_t)e1.x * D_OUT))[lane];
        ushort4 s2 = ((const ushort4*)(S + (size_t)e2.x * D_OUT))[lane];
        ushort4 s3 = ((const ushort4*)(S + (size_t)e3.x * D_OUT))[lane];
        float v0 = __int_as_float(e0.y), v1 = __int_as_float(e1.y);
        float v2 = __int_as_float(e2.y), v3 = __int_as_float(e3.y);
        a0.x += v0 * bf2f(s0.x) + v2 * bf2f(s2.x);
        a0.y += v0 * bf2f(s0.y) + v2 * bf2f(s2.y);
        a0.z += v0 * bf2f(s0.z) + v2 * bf2f(s2.z);
        a0.w += v0 * bf2f(s0.w) + v2 * bf2f(s2.w);
        a1.x += v1 * bf2f(s1.x) + v3 * bf2f(s3.x);
        a1.y += v1 * bf2f(s1.y) + v3 * bf2f(s3.y);
        a1.z += v1 * bf2f(s1.z) + v3 * bf2f(s3.z);
        a1.w += v1 * bf2f(s1.w) + v3 * bf2f(s3.w);
    }
    for (; j < end; ++j) {
        int2 e = edges[j];
        float v = __int_as_float(e.y);
        ushort4 s = ((const ushort4*)(S + (size_t)e.x * D_OUT))[lane];
        a0.x += v * bf2f(s.x);
        a0.y += v * bf2f(s.y);
        a0.z += v * bf2f(s.z);
        a0.w += v * bf2f(s.w);
    }
    a0.x += a1.x; a0.y += a1.y; a0.z += a1.z; a0.w += a1.w;
    floatx4 res = {a0.x, a0.y, a0.z, a0.w};
    __builtin_nontemporal_store(res, (floatx4*)(out + (size_t)row * D_OUT) + lane);
}

extern "C" void kernel_launch(void* const* d_in, const int* in_sizes, int n_in,
                              void* d_out, int out_size, void* d_ws, size_t ws_size,
                              hipStream_t stream) {
    const float* inputs    = (const float*)d_in[0];
    const float* weights   = (const float*)d_in[1];
    const float* bias      = (const float*)d_in[2];
    const float* edge_vals = (const float*)d_in[3];
    const int*   edge_row  = (const int*)d_in[4];
    const int*   edge_col  = (const int*)d_in[5];
    float* out = (float*)d_out;

    const int M = in_sizes[0] / D_IN;  // 50000
    const int E = in_sizes[3];         // 800000
    const int MP = ((M + 127) / 128) * 128;    // 50048 padded rows

    // Layout: S | Wt | [A16 (main only)] | edges | ptr | cnt | partials
    const size_t szS   = (size_t)M * D_OUT * 2;
    const size_t szWt  = (size_t)D_OUT * D_IN * 2;
    const size_t szA16 = (size_t)MP * D_IN * 2;
    const size_t szE   = (size_t)E * 8;
    const size_t szTail = ((size_t)((M + 4) & ~3) + M + 64) * 4;
    const bool mainPath = ws_size >= szS + szWt + szA16 + szE + szTail;

    char* ws = (char*)d_ws;
    unsigned short* S   = (unsigned short*)ws;
    unsigned short* Wt  = (unsigned short*)(ws + szS);
    unsigned short* A16 = (unsigned short*)(ws + szS + szWt);
    int2* edges  = (int2*)(ws + szS + szWt + (mainPath ? szA16 : 0));
    int*  ptr    = (int*)((char*)edges + szE);
    int*  cnt    = ptr + ((M + 4) & ~3);
    int*  partials = cnt + M;          // 16 ints, zeroed with cnt

    // 1) prep: (A->bf16 if main) + W->bf16 transposed + cnt/partials zeroing
    int NA = mainPath ? (int)((szA16 / 2) / 4096) : 0;   // 6256 | 0
    int NZ = M + 16;
    prep<<<NA + 256 + (NZ + 511) / 512, 512, 0, stream>>>(inputs, A16, weights, Wt,
                                                          cnt, M, NA, NZ);

    // 2) CSR histogram + single-dispatch global scan (decoupled lookback)
    hist_rows<<<(E + 1023) / 1024, 256, 0, stream>>>(edge_row, cnt, E);
    scan_blocks<<<(M + SCAN_B - 1) / SCAN_B, 1024, 0, stream>>>(cnt, ptr, partials, M);

    // 3) GEMM + destructive edge placement tail
    int nBuild = (E + 511) / 512;          // 1563
    if (mainPath) {
        int nGemm = (MP / 128) * 2;        // 782
        gemm_build_lds<<<nGemm + nBuild, 512, 0, stream>>>(A16, Wt, S, M, nGemm,
                                                           edge_vals, edge_row, edge_col,
                                                           ptr, edges, E);
    } else {
        int nGemm = (M + 63) / 64;         // 782
        gemm_build_reg<<<nGemm + nBuild, 512, 0, stream>>>(inputs, Wt, S, M, nGemm,
                                                           edge_vals, edge_row, edge_col,
                                                           ptr, edges, E);
    }

    // 4) aggregate (shifted CSR bounds)
    spmm_rows<<<(M + 3) / 4, 256, 0, stream>>>(S, edges, ptr, bias, out, M);
}